// Round 2
// baseline (402.262 us; speedup 1.0000x reference)
//
#include <hip/hip_runtime.h>
#include <math.h>

// ---------------------------------------------------------------------------
// 2-layer GCN via commuted form:  out_layer = (M·X)@W + b   (M = D^-1/2(A+I)D^-1/2)
// Aggregation (M·X row gather) is fused into the GEMM's LDS staging, so the
// only large scratch buffer is a1 [N x 128]. Total ws use ~27.6 MB.
// ---------------------------------------------------------------------------

__global__ __launch_bounds__(256) void k_init(int* cnt, int* cursor, int n) {
    int i = blockIdx.x * blockDim.x + threadIdx.x;
    if (i < n) { cnt[i] = 0; cursor[i] = 0; }
}

__global__ __launch_bounds__(256) void k_count(const int* __restrict__ dst, int* cnt, int e) {
    int i = blockIdx.x * blockDim.x + threadIdx.x;
    if (i < e) atomicAdd(&cnt[dst[i]], 1);
}

// Single-block exclusive scan over n counts -> rowptr[0..n]; dinv = rsqrt(cnt+1)
__global__ __launch_bounds__(1024) void k_scan(const int* __restrict__ cnt, int* __restrict__ rowptr,
                                               float* __restrict__ dinv, int n) {
    __shared__ int part[1024];
    const int t = threadIdx.x;
    const int chunk = (n + 1023) / 1024;
    const int b = t * chunk;
    const int e = min(b + chunk, n);
    int s = 0;
    for (int i = b; i < e; ++i) s += cnt[i];
    part[t] = s;
    __syncthreads();
    for (int off = 1; off < 1024; off <<= 1) {
        int v = (t >= off) ? part[t - off] : 0;
        __syncthreads();
        part[t] += v;
        __syncthreads();
    }
    int excl = part[t] - s;
    for (int i = b; i < e; ++i) {
        rowptr[i] = excl;
        excl += cnt[i];
        dinv[i] = rsqrtf((float)(cnt[i] + 1));   // +1 self-loop; deg >= 1 always
    }
    if (t == 1023) rowptr[n] = part[1023];
}

__global__ __launch_bounds__(256) void k_fill(const int* __restrict__ src, const int* __restrict__ dst,
                                              const int* __restrict__ rowptr, int* cursor,
                                              int* __restrict__ esrc, int e) {
    int i = blockIdx.x * blockDim.x + threadIdx.x;
    if (i < e) {
        int d = dst[i];
        int p = atomicAdd(&cursor[d], 1);
        esrc[rowptr[d] + p] = src[i];
    }
}

// ---------------------------------------------------------------------------
// Fused layer:  Out[r] = act( (M·X)[r] @ W + bias )
//   X: [n x 128] gather source (never aliased with Out)
//   W: [128 x COLS], bias: [COLS], Out: [n x COLS]
// Block = 256 threads, RPB node-rows per block.
// Stage 1: gather (M·X) rows into LDS transposed sM[k][r] (full K=128).
// Stage 2: GEMM vs W staged in two 64-k chunks; 4x4 register micro-tile.
// ---------------------------------------------------------------------------
template <int COLS, int RPB, bool RELU>
__global__ __launch_bounds__(256) void fused_layer(const float* __restrict__ X,
                                                   const float* __restrict__ W,
                                                   const float* __restrict__ bias,
                                                   const int* __restrict__ rowptr,
                                                   const int* __restrict__ esrc,
                                                   const float* __restrict__ dinv,
                                                   float* __restrict__ Out, int n) {
    constexpr int PAD = RPB + 4;          // row stride: 36 or 68 floats (16B multiple)
    constexpr int G   = 256 / RPB;        // threads cooperating per node row
    constexpr int SEG = 128 / G;          // features per thread in gather
    __shared__ __align__(16) float sM[128][PAD];
    __shared__ __align__(16) float sW[64][COLS];

    const int t    = threadIdx.x;
    const int row0 = blockIdx.x * RPB;

    // ---- gather staging: sM[k][r] = (M X)[row0+r][k] ----
    {
        const int r   = t / G;
        const int seg = (t % G) * SEG;
        const int d   = row0 + r;
        if (d < n) {
            const float wd = dinv[d];
            float ga[SEG];
            const float4* Xd = (const float4*)&X[(size_t)d * 128 + seg];
#pragma unroll
            for (int q = 0; q < SEG / 4; ++q) {
                float4 v = Xd[q];
                ga[q * 4 + 0] = wd * v.x; ga[q * 4 + 1] = wd * v.y;
                ga[q * 4 + 2] = wd * v.z; ga[q * 4 + 3] = wd * v.w;
            }
            const int beg = rowptr[d], end = rowptr[d + 1];
            for (int j = beg; j < end; ++j) {
                int   s  = esrc[j];
                float ws = dinv[s];
                const float4* Xs = (const float4*)&X[(size_t)s * 128 + seg];
#pragma unroll
                for (int q = 0; q < SEG / 4; ++q) {
                    float4 v = Xs[q];
                    ga[q * 4 + 0] += ws * v.x; ga[q * 4 + 1] += ws * v.y;
                    ga[q * 4 + 2] += ws * v.z; ga[q * 4 + 3] += ws * v.w;
                }
            }
#pragma unroll
            for (int q = 0; q < SEG; ++q) sM[seg + q][r] = wd * ga[q];
        }
        // rows with d >= n: sM garbage, stores guarded below
    }

    // ---- GEMM: acc[4][4] per thread ----
    const int tcx = t % (COLS / 4);       // col group
    const int tcy = t / (COLS / 4);       // row group (covers RPB rows)
    float acc[4][4] = {};

    for (int kc = 0; kc < 128; kc += 64) {
        __syncthreads();                  // sM ready (1st it) / sW reuse safe (2nd it)
        const float4* Wf4 = (const float4*)(W + (size_t)kc * COLS);
        float4* sWf4 = (float4*)&sW[0][0];
        for (int f = t; f < 64 * COLS / 4; f += 256) sWf4[f] = Wf4[f];
        __syncthreads();
#pragma unroll 8
        for (int k = 0; k < 64; ++k) {
            float4 a = *(const float4*)&sM[kc + k][tcy * 4];
            float4 b = *(const float4*)&sW[k][tcx * 4];
            float av[4] = {a.x, a.y, a.z, a.w};
            float bv[4] = {b.x, b.y, b.z, b.w};
#pragma unroll
            for (int i = 0; i < 4; ++i)
#pragma unroll
                for (int j = 0; j < 4; ++j) acc[i][j] += av[i] * bv[j];
        }
    }

    // ---- epilogue: bias (+ReLU), store ----
    float4 bv4 = *(const float4*)&bias[tcx * 4];
    float bb[4] = {bv4.x, bv4.y, bv4.z, bv4.w};
#pragma unroll
    for (int i = 0; i < 4; ++i) {
        int r = row0 + tcy * 4 + i;
        if (r < n) {
            float o[4];
#pragma unroll
            for (int j = 0; j < 4; ++j) {
                o[j] = acc[i][j] + bb[j];
                if (RELU) o[j] = fmaxf(o[j], 0.f);
            }
            *(float4*)&Out[(size_t)r * COLS + tcx * 4] = make_float4(o[0], o[1], o[2], o[3]);
        }
    }
}

// ---------------------------------------------------------------------------

extern "C" void kernel_launch(void* const* d_in, const int* in_sizes, int n_in,
                              void* d_out, int out_size, void* d_ws, size_t ws_size,
                              hipStream_t stream) {
    const float* x  = (const float*)d_in[0];
    const int*   ei = (const int*)d_in[1];
    const float* W1 = (const float*)d_in[2];
    const float* b1 = (const float*)d_in[3];
    const float* W2 = (const float*)d_in[4];
    const float* b2 = (const float*)d_in[5];
    float* out = (float*)d_out;

    const int N = in_sizes[0] / 128;
    const int E = in_sizes[1] / 2;
    const int* src = ei;
    const int* dst = ei + E;

    // workspace carve (256B aligned)
    size_t off = 0;
    char* base = (char*)d_ws;
    auto carve = [&](size_t bytes) -> void* {
        void* p = base + off;
        off += (bytes + 255) & ~(size_t)255;
        return p;
    };
    int*   cnt    = (int*)carve((size_t)N * 4);
    int*   cursor = (int*)carve((size_t)N * 4);
    int*   rowptr = (int*)carve((size_t)(N + 1) * 4);
    float* dinv   = (float*)carve((size_t)N * 4);
    int*   esrc   = (int*)carve((size_t)E * 4);
    float* a1     = (float*)carve((size_t)N * 128 * 4);

    if (off > ws_size) return;  // diagnostic guard: clean absmax-fail instead of GPU fault

    // 1) degree histogram + CSR build
    k_init <<<(N + 255) / 256, 256, 0, stream>>>(cnt, cursor, N);
    k_count<<<(E + 255) / 256, 256, 0, stream>>>(dst, cnt, E);
    k_scan <<<1, 1024, 0, stream>>>(cnt, rowptr, dinv, N);
    k_fill <<<(E + 255) / 256, 256, 0, stream>>>(src, dst, rowptr, cursor, esrc, E);

    // 2) layer 1: a1 = relu((M x) @ W1 + b1)   [RPB=32, LDS 50.0 KB]
    fused_layer<128, 32, true><<<(N + 31) / 32, 256, 0, stream>>>(
        x, W1, b1, rowptr, esrc, dinv, a1, N);

    // 3) layer 2: out = (M a1) @ W2 + b2       [RPB=64, LDS 50.0 KB]
    fused_layer<64, 64, false><<<(N + 63) / 64, 256, 0, stream>>>(
        a1, W2, b2, rowptr, esrc, dinv, out, N);
}

// Round 3
// 307.148 us; speedup vs baseline: 1.3097x; 1.3097x over previous
//
#include <hip/hip_runtime.h>
#include <math.h>

// ---------------------------------------------------------------------------
// 2-layer GCN via commuted form:  out_layer = (M·X)@W + b   (M = D^-1/2(A+I)D^-1/2)
// Aggregation (M·X row gather) fused into the GEMM's LDS staging.
// CSR build per call; scan parallelized 3-phase (R2: was 108us single-block).
// ---------------------------------------------------------------------------

#define SCAN_CHUNK 2048   // elements per block in the scan phases

__global__ __launch_bounds__(256) void k_init(int* cnt, int n) {
    int i = blockIdx.x * blockDim.x + threadIdx.x;
    if (i < n) cnt[i] = 0;
}

__global__ __launch_bounds__(256) void k_count(const int* __restrict__ dst, int* cnt, int e) {
    int i = blockIdx.x * blockDim.x + threadIdx.x;
    if (i < e) atomicAdd(&cnt[dst[i]], 1);
}

// Phase A: per-block sums of cnt (SCAN_CHUNK per block)
__global__ __launch_bounds__(256) void k_blksum(const int* __restrict__ cnt, int* __restrict__ blkSum, int n) {
    __shared__ int part[256];
    const int t = threadIdx.x;
    const int base = blockIdx.x * SCAN_CHUNK + t * 8;
    int s = 0;
#pragma unroll
    for (int q = 0; q < 8; ++q) {
        int i = base + q;
        s += (i < n) ? cnt[i] : 0;
    }
    part[t] = s;
    __syncthreads();
    for (int off = 128; off > 0; off >>= 1) {
        if (t < off) part[t] += part[t + off];
        __syncthreads();
    }
    if (t == 0) blkSum[blockIdx.x] = part[0];
}

// Phase B: single block exclusive-scans blkSum[nb] (nb <= 256) -> blkoff; rowptr[n] = total
__global__ __launch_bounds__(256) void k_scanblk(const int* __restrict__ blkSum, int* __restrict__ blkoff,
                                                 int* __restrict__ rowptr, int nb, int n) {
    __shared__ int part[256];
    const int t = threadIdx.x;
    int v = (t < nb) ? blkSum[t] : 0;
    part[t] = v;
    __syncthreads();
    for (int off = 1; off < 256; off <<= 1) {
        int u = (t >= off) ? part[t - off] : 0;
        __syncthreads();
        part[t] += u;
        __syncthreads();
    }
    if (t < nb) blkoff[t] = part[t] - v;
    if (t == 255) rowptr[n] = part[255];
}

// Phase C: per-block local exclusive scan + blkoff -> rowptr; also dinv, cursor=0
__global__ __launch_bounds__(256) void k_apply(const int* __restrict__ cnt, const int* __restrict__ blkoff,
                                               int* __restrict__ rowptr, float* __restrict__ dinv,
                                               int* __restrict__ cursor, int n) {
    __shared__ int part[256];
    const int t = threadIdx.x;
    const int base = blockIdx.x * SCAN_CHUNK + t * 8;
    int v[8];
    int s = 0;
#pragma unroll
    for (int q = 0; q < 8; ++q) {
        int i = base + q;
        v[q] = (i < n) ? cnt[i] : 0;
        s += v[q];
    }
    part[t] = s;
    __syncthreads();
    for (int off = 1; off < 256; off <<= 1) {
        int u = (t >= off) ? part[t - off] : 0;
        __syncthreads();
        part[t] += u;
        __syncthreads();
    }
    int run = part[t] - s + blkoff[blockIdx.x];
#pragma unroll
    for (int q = 0; q < 8; ++q) {
        int i = base + q;
        if (i < n) {
            rowptr[i] = run;
            dinv[i]   = rsqrtf((float)(v[q] + 1));   // +1 self-loop
            cursor[i] = 0;
            run += v[q];
        }
    }
}

__global__ __launch_bounds__(256) void k_fill(const int* __restrict__ src, const int* __restrict__ dst,
                                              const int* __restrict__ rowptr, int* cursor,
                                              int* __restrict__ esrc, int e) {
    int i = blockIdx.x * blockDim.x + threadIdx.x;
    if (i < e) {
        int d = dst[i];
        int p = atomicAdd(&cursor[d], 1);
        esrc[rowptr[d] + p] = src[i];
    }
}

// ---------------------------------------------------------------------------
// Fused layer:  Out[r] = act( (M·X)[r] @ W + bias )
// Block = 256 threads, RPB node-rows per block.
// Stage 1: gather (M·X) rows into LDS transposed sM[k][r] (full K=128).
// Stage 2: GEMM vs W staged in two 64-k chunks; 4x4 register micro-tile.
// ---------------------------------------------------------------------------
template <int COLS, int RPB, bool RELU>
__global__ __launch_bounds__(256) void fused_layer(const float* __restrict__ X,
                                                   const float* __restrict__ W,
                                                   const float* __restrict__ bias,
                                                   const int* __restrict__ rowptr,
                                                   const int* __restrict__ esrc,
                                                   const float* __restrict__ dinv,
                                                   float* __restrict__ Out, int n) {
    constexpr int PAD = RPB + 4;          // row stride: 36 or 68 floats (16B multiple)
    constexpr int G   = 256 / RPB;        // threads cooperating per node row
    constexpr int SEG = 128 / G;          // features per thread in gather
    __shared__ __align__(16) float sM[128][PAD];
    __shared__ __align__(16) float sW[64][COLS];

    const int t    = threadIdx.x;
    const int row0 = blockIdx.x * RPB;

    // ---- gather staging: sM[k][r] = (M X)[row0+r][k] ----
    {
        const int r   = t / G;
        const int seg = (t % G) * SEG;
        const int d   = row0 + r;
        if (d < n) {
            const float wd = dinv[d];
            float ga[SEG];
            const float4* Xd = (const float4*)&X[(size_t)d * 128 + seg];
#pragma unroll
            for (int q = 0; q < SEG / 4; ++q) {
                float4 v = Xd[q];
                ga[q * 4 + 0] = wd * v.x; ga[q * 4 + 1] = wd * v.y;
                ga[q * 4 + 2] = wd * v.z; ga[q * 4 + 3] = wd * v.w;
            }
            const int beg = rowptr[d], end = rowptr[d + 1];
            for (int j = beg; j < end; ++j) {
                int   s  = esrc[j];
                float ws = dinv[s];
                const float4* Xs = (const float4*)&X[(size_t)s * 128 + seg];
#pragma unroll
                for (int q = 0; q < SEG / 4; ++q) {
                    float4 v = Xs[q];
                    ga[q * 4 + 0] += ws * v.x; ga[q * 4 + 1] += ws * v.y;
                    ga[q * 4 + 2] += ws * v.z; ga[q * 4 + 3] += ws * v.w;
                }
            }
#pragma unroll
            for (int q = 0; q < SEG; ++q) sM[seg + q][r] = wd * ga[q];
        }
    }

    // ---- GEMM: acc[4][4] per thread ----
    const int tcx = t % (COLS / 4);       // col group
    const int tcy = t / (COLS / 4);       // row group (covers RPB rows)
    float acc[4][4] = {};

    for (int kc = 0; kc < 128; kc += 64) {
        __syncthreads();                  // sM ready (1st it) / sW reuse safe (2nd it)
        const float4* Wf4 = (const float4*)(W + (size_t)kc * COLS);
        float4* sWf4 = (float4*)&sW[0][0];
        for (int f = t; f < 64 * COLS / 4; f += 256) sWf4[f] = Wf4[f];
        __syncthreads();
#pragma unroll 8
        for (int k = 0; k < 64; ++k) {
            float4 a = *(const float4*)&sM[kc + k][tcy * 4];
            float4 b = *(const float4*)&sW[k][tcx * 4];
            float av[4] = {a.x, a.y, a.z, a.w};
            float bv[4] = {b.x, b.y, b.z, b.w};
#pragma unroll
            for (int i = 0; i < 4; ++i)
#pragma unroll
                for (int j = 0; j < 4; ++j) acc[i][j] += av[i] * bv[j];
        }
    }

    // ---- epilogue: bias (+ReLU), store ----
    float4 bv4 = *(const float4*)&bias[tcx * 4];
    float bb[4] = {bv4.x, bv4.y, bv4.z, bv4.w};
#pragma unroll
    for (int i = 0; i < 4; ++i) {
        int r = row0 + tcy * 4 + i;
        if (r < n) {
            float o[4];
#pragma unroll
            for (int j = 0; j < 4; ++j) {
                o[j] = acc[i][j] + bb[j];
                if (RELU) o[j] = fmaxf(o[j], 0.f);
            }
            *(float4*)&Out[(size_t)r * COLS + tcx * 4] = make_float4(o[0], o[1], o[2], o[3]);
        }
    }
}

// ---------------------------------------------------------------------------

extern "C" void kernel_launch(void* const* d_in, const int* in_sizes, int n_in,
                              void* d_out, int out_size, void* d_ws, size_t ws_size,
                              hipStream_t stream) {
    const float* x  = (const float*)d_in[0];
    const int*   ei = (const int*)d_in[1];
    const float* W1 = (const float*)d_in[2];
    const float* b1 = (const float*)d_in[3];
    const float* W2 = (const float*)d_in[4];
    const float* b2 = (const float*)d_in[5];
    float* out = (float*)d_out;

    const int N = in_sizes[0] / 128;
    const int E = in_sizes[1] / 2;
    const int* src = ei;
    const int* dst = ei + E;
    const int NB = (N + SCAN_CHUNK - 1) / SCAN_CHUNK;   // 25 for N=50000 (<=256 req'd)

    // workspace carve (256B aligned)
    size_t off = 0;
    char* base = (char*)d_ws;
    auto carve = [&](size_t bytes) -> void* {
        void* p = base + off;
        off += (bytes + 255) & ~(size_t)255;
        return p;
    };
    int*   cnt    = (int*)carve((size_t)N * 4);
    int*   cursor = (int*)carve((size_t)N * 4);
    int*   rowptr = (int*)carve((size_t)(N + 1) * 4);
    float* dinv   = (float*)carve((size_t)N * 4);
    int*   esrc   = (int*)carve((size_t)E * 4);
    int*   blkSum = (int*)carve((size_t)NB * 4);
    int*   blkoff = (int*)carve((size_t)NB * 4);
    float* a1     = (float*)carve((size_t)N * 128 * 4);

    if (off > ws_size) return;  // diagnostic guard

    // 1) degree histogram + parallel CSR build
    k_init   <<<(N + 255) / 256, 256, 0, stream>>>(cnt, N);
    k_count  <<<(E + 255) / 256, 256, 0, stream>>>(dst, cnt, E);
    k_blksum <<<NB, 256, 0, stream>>>(cnt, blkSum, N);
    k_scanblk<<<1, 256, 0, stream>>>(blkSum, blkoff, rowptr, NB, N);
    k_apply  <<<NB, 256, 0, stream>>>(cnt, blkoff, rowptr, dinv, cursor, N);
    k_fill   <<<(E + 255) / 256, 256, 0, stream>>>(src, dst, rowptr, cursor, esrc, E);

    // 2) layer 1: a1 = relu((M x) @ W1 + b1)   [RPB=32]
    fused_layer<128, 32, true><<<(N + 31) / 32, 256, 0, stream>>>(
        x, W1, b1, rowptr, esrc, dinv, a1, N);

    // 3) layer 2: out = (M a1) @ W2 + b2       [RPB=64]
    fused_layer<64, 64, false><<<(N + 63) / 64, 256, 0, stream>>>(
        a1, W2, b2, rowptr, esrc, dinv, out, N);
}